// Round 12
// baseline (316.371 us; speedup 1.0000x reference)
//
#include <hip/hip_runtime.h>
#include <stdint.h>

// Calibration-histogram kernel for MI355X (round 11).
// probs: (1,2,4096,4096) f32, labels: (1,1,4096,4096) i32.
// Outputs (flat, 90 f32): count0[15], csum0[15], asum0[15], count1[15], csum1[15], asum1[15].
//
// Rounds 5/7/10 post-mortem: ALL LDS-RMW-per-update variants (atomic u64,
// plain u64, plain u32 + prefetch) land at 96-140 us: the data-dependent
// ds_read->add->ds_write chain is latency-bound at ~100+ cyc/link and does
// not overlap, regardless of occupancy. Fix: NO LDS in the hot loop.
// Per-thread REGISTER accumulators: 2ch x 16 bins packed u32
//   [31:14] csum (fixed-point 2^11) | [13:7] asum | [6:0] count
// updated via fully-unrolled branchless 16-way select (static indices ->
// stays in VGPRs). 1280 blocks x 256 thr -> <=13 iters/thread:
// count<=52<128, csum<=52*2048=106496<2^18 -> carry-safe.
// LDS touched once at the end: dump 32 regs -> 32KB, bank-rotated merge
// (proven in round 8) + 8-lane shfl reduce + 90 global float atomics.

#define NBINS 15

__global__ void zero_out_kernel(float* out, int n) {
    int i = blockIdx.x * blockDim.x + threadIdx.x;
    if (i < n) out[i] = 0.0f;
}

__device__ __forceinline__ unsigned pack_u32(float c, int match, int* bin_out) {
    // Reference: bin i holds conf in (b[i], b[i+1]]; conf==0 -> invalid.
    bool valid = (c > 0.0f) && (c <= 1.0f);
    float cb = fmaxf(fminf(c * 15.0f, 14.0f), 0.0f);   // clamped bin, branchless
    *bin_out = (int)cb;
    unsigned cf = __float2uint_rn(fmaxf(c, 0.0f) * 2048.0f);  // conf * 2^11
    unsigned v = (cf << 14) | ((match ? 1u : 0u) << 7) | 1u;
    return valid ? v : 0u;   // invalid -> add zero, uniform control flow
}

// Branchless scatter into 16 register accumulators. Macro (not function)
// so the accumulator array is always accessed with compile-time indices
// after unrolling -> guaranteed VGPR allocation (no scratch).
#define UPDATE16(acc, c, m)                                      \
    do {                                                         \
        int _bin; unsigned _v = pack_u32((c), (m), &_bin);       \
        _Pragma("unroll")                                        \
        for (int _k = 0; _k < 16; ++_k)                          \
            (acc)[_k] += (_bin == _k) ? _v : 0u;                 \
    } while (0)

__global__ __launch_bounds__(256, 4) void calib_hist_kernel(
        const float* __restrict__ probs, const int* __restrict__ labels,
        float* __restrict__ out, int npix) {
    unsigned accA[16], accB[16];   // ch0 / ch1 register histograms
    #pragma unroll
    for (int k = 0; k < 16; ++k) { accA[k] = 0u; accB[k] = 0u; }

    const float4* p0 = (const float4*)probs;           // channel 0
    const float4* p1 = (const float4*)(probs + npix);  // channel 1
    const int4*   lb = (const int4*)labels;
    int nvec   = npix >> 2;
    int stride = gridDim.x * blockDim.x;
    int tid    = threadIdx.x;

    // Simple grid-stride loop: compiler pipelines the 3 dwordx4 loads
    // against the pure-VALU select tree (no LDS, no waitcnt chains).
    for (int i = blockIdx.x * blockDim.x + tid; i < nvec; i += stride) {
        float4 a = p0[i];
        float4 b = p1[i];
        int4   l = lb[i];
        UPDATE16(accA, a.x, l.x == 0);
        UPDATE16(accB, b.x, l.x == 1);
        UPDATE16(accA, a.y, l.y == 0);
        UPDATE16(accB, b.y, l.y == 1);
        UPDATE16(accA, a.z, l.z == 0);
        UPDATE16(accB, b.z, l.z == 1);
        UPDATE16(accA, a.w, l.w == 0);
        UPDATE16(accB, b.w, l.w == 1);
    }

    // One-shot LDS dump: hist[entry][tid], entry = ch*16+bin.
    // bank(word = e*256+tid) = tid mod 32 -> conflict-free stores.
    __shared__ unsigned hist[32 * 256];   // 32 KB
    #pragma unroll
    for (int k = 0; k < 16; ++k) {
        hist[k * 256 + tid]        = accA[k];
        hist[(16 + k) * 256 + tid] = accB[k];
    }
    __syncthreads();

    // Merge (round-8 proven): thread h owns entry e=h>>3, column chunk
    // (h&7)*32 rotated by h -> 2 lanes/bank (free). Unpack BEFORE summing.
    {
        int h = tid;
        int e = h >> 3;                    // 0..31
        unsigned cnt = 0, asum = 0, csum = 0;
        int base = (h & 7) * 32;
        #pragma unroll
        for (int j = 0; j < 32; ++j) {
            int col = base + ((j + h) & 31);
            unsigned x = hist[e * 256 + col];
            cnt  += x & 0x7Fu;
            asum += (x >> 7) & 0x7Fu;
            csum += x >> 14;
        }
        cnt  += __shfl_xor(cnt, 1); asum += __shfl_xor(asum, 1); csum += __shfl_xor(csum, 1);
        cnt  += __shfl_xor(cnt, 2); asum += __shfl_xor(asum, 2); csum += __shfl_xor(csum, 2);
        cnt  += __shfl_xor(cnt, 4); asum += __shfl_xor(asum, 4); csum += __shfl_xor(csum, 4);
        int ch = e >> 4, bin = e & 15;
        if ((h & 7) == 0 && bin < NBINS) {
            float* obase = out + ch * 45;
            atomicAdd(obase + bin,             (float)cnt);
            atomicAdd(obase + NBINS + bin,     (float)csum * (1.0f / 2048.0f));
            atomicAdd(obase + 2 * NBINS + bin, (float)asum);
        }
    }
}

extern "C" void kernel_launch(void* const* d_in, const int* in_sizes, int n_in,
                              void* d_out, int out_size, void* d_ws, size_t ws_size,
                              hipStream_t stream) {
    const float* probs  = (const float*)d_in[0];
    const int*   labels = (const int*)d_in[1];
    float*       out    = (float*)d_out;
    int npix = in_sizes[1];  // 4096*4096 pixels; probs has 2*npix elements

    zero_out_kernel<<<(out_size + 127) / 128, 128, 0, stream>>>(out, out_size);

    // 1280 blocks = 5 blocks/CU exactly resident (32KB LDS each).
    // <=13 iters/thread keeps packed fields carry-safe (count<=52<128).
    calib_hist_kernel<<<1280, 256, 0, stream>>>(probs, labels, out, npix);
}